// Round 4
// baseline (2437.307 us; speedup 1.0000x reference)
//
#include <hip/hip_runtime.h>
#include <hip/hip_bf16.h>
#include <math.h>

#define T_ 12
#define E_ 8192
#define H_ 256
#define V_ 800
#define B_ 256
#define NB_ 8
#define M_ (T_*E_)
#define TM 16            // message rows per block per step
#define HP (H_ + 8)      // bf16 LDS row pad
#define NBLK 512         // persistent grid: 2 blocks/CU on 256 CUs (guaranteed by VGPR cap)

typedef __attribute__((ext_vector_type(8))) short bf16x8;
typedef __attribute__((ext_vector_type(4))) float f32x4;

#define LOG2E_ 1.44269504088896f

// fast native transcendentals (v_exp_f32 = 2^x, v_rcp_f32)
__device__ __forceinline__ float fexp2_(float x) { return __builtin_amdgcn_exp2f(x); }
__device__ __forceinline__ float frcp_(float x)  { return __builtin_amdgcn_rcpf(x); }
__device__ __forceinline__ float fsig(float x) {
    return frcp_(1.0f + fexp2_(-LOG2E_ * x));
}
__device__ __forceinline__ float ftanh(float x) {
    // tanh(x) = 1 - 2/(exp(2x)+1); large |x| saturates correctly via inf/0
    return 1.0f - 2.0f * frcp_(fexp2_(2.0f * LOG2E_ * x) + 1.0f);
}

// RNE f32 -> bf16 bits
__device__ __forceinline__ short f2bf(float x) {
    unsigned u = __float_as_uint(x);
    unsigned r = (u + 0x7fffu + ((u >> 16) & 1u)) >> 16;
    return (short)r;
}
__device__ __forceinline__ float bf2f(unsigned short s) {
    return __uint_as_float(((unsigned)s) << 16);
}
// packed word: lo16 -> float via <<16, hi16 -> float via mask
__device__ __forceinline__ float hu_h(unsigned v) { return __uint_as_float(v << 16); }
__device__ __forceinline__ float hu_u(unsigned v) { return __uint_as_float(v & 0xffff0000u); }
__device__ __forceinline__ unsigned pack2(float a, float b) {
    return (unsigned)(unsigned short)f2bf(a) | ((unsigned)(unsigned short)f2bf(b) << 16);
}

// Device-scope grid barrier for a fully-resident grid (plain launch, no coop API).
// Release: __syncthreads drains this block's stores to its XCD L2 (compiler emits
// vmcnt(0) before s_barrier); thread0's __threadfence writes that L2 back device-
// wide before the arrival atomic. Acquire: spin with acquire loads, then an
// all-thread __threadfence invalidates L1/L2 so next-step gathers see fresh data.
__device__ __forceinline__ void gbar(unsigned* cnt, unsigned target) {
    __syncthreads();
    if (threadIdx.x == 0) {
        __threadfence();
        __hip_atomic_fetch_add(cnt, 1u, __ATOMIC_RELEASE, __HIP_MEMORY_SCOPE_AGENT);
        while (__hip_atomic_load(cnt, __ATOMIC_ACQUIRE, __HIP_MEMORY_SCOPE_AGENT) < target)
            __builtin_amdgcn_s_sleep(2);
    }
    __syncthreads();
    __threadfence();
}

// Weight prep (+ slot-0 init and barrier-counter reset folded into block 768).
// Wzt[n][k] = Wz[256+k][n], Wht[n][k] = Wh[256+k][n], Urt[n][k] = Ur[k][n], bf16.
__global__ __launch_bounds__(256) void k_wconv(
    const float* __restrict__ Wz, const float* __restrict__ Wh, const float* __restrict__ Ur,
    short* __restrict__ Wzt, short* __restrict__ Wht, short* __restrict__ Urt,
    float* __restrict__ h, unsigned* __restrict__ hu, unsigned* __restrict__ bar)
{
    if (blockIdx.x == 768) {            // zero padding row (slot 0) of h and hu
        h[threadIdx.x] = 0.0f;
        hu[threadIdx.x] = 0u;
        if (threadIdx.x == 0) bar[0] = 0u;   // re-zero barrier each graph replay
        return;
    }
    int tid = blockIdx.x * 256 + threadIdx.x;
    int w = tid >> 16;
    int idx = tid & 65535;
    int n = idx >> 8, k = idx & 255;
    if (w == 0)      Wzt[idx] = f2bf(Wz[(size_t)(256 + k) * H_ + n]);
    else if (w == 1) Wht[idx] = f2bf(Wh[(size_t)(256 + k) * H_ + n]);
    else             Urt[idx] = f2bf(Ur[(size_t)k * H_ + n]);
}

// Batched prelude: eW*[v] = emb[v] @ Btop + bias  (blockIdx.z selects table)
__global__ __launch_bounds__(256) void gemm_pre(
    const float* __restrict__ emb,
    const float* __restrict__ Wr, const float* __restrict__ Wz,
    const float* __restrict__ Wh, const float* __restrict__ Wo,
    const float* __restrict__ bur, const float* __restrict__ bz,
    const float* __restrict__ bh, const float* __restrict__ bo,
    float* __restrict__ eWr, float* __restrict__ eWz,
    float* __restrict__ eWh, float* __restrict__ eWo)
{
    const float* Bm; const float* bias; float* C;
    switch (blockIdx.z) {
        case 0: Bm = Wr; bias = bur; C = eWr; break;
        case 1: Bm = Wz; bias = bz;  C = eWz; break;
        case 2: Bm = Wh; bias = bh;  C = eWh; break;
        default: Bm = Wo; bias = bo; C = eWo; break;
    }
    __shared__ float As[16][64];
    __shared__ float Bs[16][64];
    const int tid = threadIdx.x;
    const int bm = blockIdx.x * 64;
    const int bn = blockIdx.y * 64;
    const int a_m = tid & 63;
    const int a_k = (tid >> 6) << 2;
    const int b_k = tid >> 4;
    const int b_n = (tid & 15) << 2;
    const int tx = tid & 15, ty = tid >> 4;

    float acc[4][4] = {};
    const bool a_ok = (bm + a_m) < V_;
    const float* Ap = emb + (size_t)(bm + a_m) * H_ + a_k;
    const float* Bp = Bm + (size_t)b_k * H_ + bn + b_n;

    for (int k0 = 0; k0 < H_; k0 += 16) {
        float4 av = a_ok ? *(const float4*)(Ap + k0) : make_float4(0.f, 0.f, 0.f, 0.f);
        float4 bv = *(const float4*)(Bp + (size_t)k0 * H_);
        __syncthreads();
        As[a_k + 0][a_m] = av.x;
        As[a_k + 1][a_m] = av.y;
        As[a_k + 2][a_m] = av.z;
        As[a_k + 3][a_m] = av.w;
        *(float4*)&Bs[b_k][b_n] = bv;
        __syncthreads();
#pragma unroll
        for (int k = 0; k < 16; ++k) {
            const float4 a4 = *(const float4*)&As[k][ty << 2];
            const float4 b4 = *(const float4*)&Bs[k][tx << 2];
            const float ar[4] = {a4.x, a4.y, a4.z, a4.w};
            const float br[4] = {b4.x, b4.y, b4.z, b4.w};
#pragma unroll
            for (int i = 0; i < 4; ++i)
#pragma unroll
                for (int j = 0; j < 4; ++j)
                    acc[i][j] = fmaf(ar[i], br[j], acc[i][j]);
        }
    }

    const int col = bn + (tx << 2);
#pragma unroll
    for (int i = 0; i < 4; ++i) {
        const int row = bm + (ty << 2) + i;
        if (row >= V_) break;
        *(float4*)(C + (size_t)row * H_ + col) =
            make_float4(acc[i][0] + bias[col], acc[i][1] + bias[col + 1],
                        acc[i][2] + bias[col + 2], acc[i][3] + bias[col + 3]);
    }
}

// Pack epilogue tables: eWzh = {lo16: bf16(eWz), hi16: bf16(eWh)}
__global__ __launch_bounds__(256) void k_pack(
    const float* __restrict__ eWz, const float* __restrict__ eWh,
    unsigned* __restrict__ eWzh)
{
    const int i = blockIdx.x * 256 + threadIdx.x;   // V_*H_ = 204800 = 800*256
    eWzh[i] = pack2(eWz[i], eWh[i]);
}

// Persistent kernel: all 12 steps + root aggregation, custom grid barrier between
// steps. 512 blocks x 512 threads; __launch_bounds__(512,4) caps VGPR at 128 ->
// 16 waves/CU -> exactly 2 blocks/CU co-resident on 256 CUs (barrier is safe).
__global__ __launch_bounds__(512, 4) void k_steps_all(
    const int* __restrict__ x_ids, const int* __restrict__ nei_idx,
    float* __restrict__ h, unsigned* __restrict__ hu,
    const float* __restrict__ eWr, const unsigned* __restrict__ eWzh,
    const short* __restrict__ Wzt, const short* __restrict__ Wht,
    const short* __restrict__ Urt,
    const int* __restrict__ root_wid, const int* __restrict__ root_nei,
    const float* __restrict__ eWo, const float* __restrict__ Wo,
    float* __restrict__ root_out, unsigned* __restrict__ bar)
{
    __shared__ int   idx[TM][NB_];
    __shared__ int   xw[TM];
    __shared__ short shB[TM][HP];   // sumh bf16 (A-frag + epilogue linear term)
    __shared__ short sgB[TM][HP];   // sumg bf16 (A-frag)
    __shared__ short hB[TM][HP];    // h_t bf16 (A-frag Ur + hu pack)

    const int tid = threadIdx.x;
    const int e0 = blockIdx.x * TM;
    const int lane = tid & 63;
    const int wave = tid >> 6;           // 0..7
    const int n0 = wave * 32;
    const int quad = lane >> 4, c = lane & 15;
    const int kq = quad * 8;

    for (int t = 0; t < T_; ++t) {
        if (tid < TM * NB_) {
            int r = tid >> 3, j = tid & 7;
            idx[r][j] = nei_idx[((size_t)t * E_ + e0 + r) * NB_ + j];
        }
        if (tid < TM) xw[tid] = x_ids[t * E_ + e0 + tid];
        __syncthreads();

        // ---- gather: thread = (4-col group, row pair); uint4 loads, 16 in flight ----
        {
            const int c0 = (tid & 63) * 4;       // 64 col-groups x 4 cols = 256 cols
            const int ra = (tid >> 6) * 2;       // 8 row-pairs = 16 rows
            const int rb = ra + 1;
            if (t == 0) {
                // all neighbor slots are the zero pad at t=0
                *(uint2*)&shB[ra][c0] = make_uint2(0u, 0u);
                *(uint2*)&sgB[ra][c0] = make_uint2(0u, 0u);
                *(uint2*)&shB[rb][c0] = make_uint2(0u, 0u);
                *(uint2*)&sgB[rb][c0] = make_uint2(0u, 0u);
            } else {
                uint4 va[NB_], vb[NB_];
#pragma unroll
                for (int j = 0; j < NB_; ++j)
                    va[j] = *(const uint4*)(hu + (size_t)idx[ra][j] * H_ + c0);
#pragma unroll
                for (int j = 0; j < NB_; ++j)
                    vb[j] = *(const uint4*)(hu + (size_t)idx[rb][j] * H_ + c0);
                const float4 r1a = *(const float4*)(eWr + (size_t)xw[ra] * H_ + c0);
                const float4 r1b = *(const float4*)(eWr + (size_t)xw[rb] * H_ + c0);

                float sa0 = 0.f, sa1 = 0.f, sa2 = 0.f, sa3 = 0.f;
                float ga0 = 0.f, ga1 = 0.f, ga2 = 0.f, ga3 = 0.f;
#pragma unroll
                for (int j = 0; j < NB_; ++j) {
                    const float h0 = hu_h(va[j].x); sa0 += h0;
                    ga0 = fmaf(fsig(r1a.x + hu_u(va[j].x)), h0, ga0);
                    const float h1 = hu_h(va[j].y); sa1 += h1;
                    ga1 = fmaf(fsig(r1a.y + hu_u(va[j].y)), h1, ga1);
                    const float h2 = hu_h(va[j].z); sa2 += h2;
                    ga2 = fmaf(fsig(r1a.z + hu_u(va[j].z)), h2, ga2);
                    const float h3 = hu_h(va[j].w); sa3 += h3;
                    ga3 = fmaf(fsig(r1a.w + hu_u(va[j].w)), h3, ga3);
                }
                *(uint2*)&shB[ra][c0] = make_uint2(pack2(sa0, sa1), pack2(sa2, sa3));
                *(uint2*)&sgB[ra][c0] = make_uint2(pack2(ga0, ga1), pack2(ga2, ga3));

                float sb0 = 0.f, sb1 = 0.f, sb2 = 0.f, sb3 = 0.f;
                float gb0 = 0.f, gb1 = 0.f, gb2 = 0.f, gb3 = 0.f;
#pragma unroll
                for (int j = 0; j < NB_; ++j) {
                    const float h0 = hu_h(vb[j].x); sb0 += h0;
                    gb0 = fmaf(fsig(r1b.x + hu_u(vb[j].x)), h0, gb0);
                    const float h1 = hu_h(vb[j].y); sb1 += h1;
                    gb1 = fmaf(fsig(r1b.y + hu_u(vb[j].y)), h1, gb1);
                    const float h2 = hu_h(vb[j].z); sb2 += h2;
                    gb2 = fmaf(fsig(r1b.z + hu_u(vb[j].z)), h2, gb2);
                    const float h3 = hu_h(vb[j].w); sb3 += h3;
                    gb3 = fmaf(fsig(r1b.w + hu_u(vb[j].w)), h3, gb3);
                }
                *(uint2*)&shB[rb][c0] = make_uint2(pack2(sb0, sb1), pack2(sb2, sb3));
                *(uint2*)&sgB[rb][c0] = make_uint2(pack2(gb0, gb1), pack2(gb2, gb3));
            }
        }
        __syncthreads();

        // ---- MFMA + in-register epilogue: wave owns 32-col strip, both Z and H ----
        f32x4 accZ[2], accH[2];
#pragma unroll
        for (int i = 0; i < 2; ++i) { accZ[i] = (f32x4)(0.0f); accH[i] = (f32x4)(0.0f); }

#pragma unroll
        for (int k0 = 0; k0 < H_; k0 += 32) {
            const bf16x8 a1 = *(const bf16x8*)&shB[c][k0 + kq];
            const bf16x8 a2 = *(const bf16x8*)&sgB[c][k0 + kq];
#pragma unroll
            for (int ni = 0; ni < 2; ++ni) {
                const size_t boff = (size_t)(n0 + ni * 16 + c) * H_ + k0 + kq;
                const bf16x8 b1 = *(const bf16x8*)(Wzt + boff);
                const bf16x8 b2 = *(const bf16x8*)(Wht + boff);
                accZ[ni] = __builtin_amdgcn_mfma_f32_16x16x32_bf16(a1, b1, accZ[ni], 0, 0, 0);
                accH[ni] = __builtin_amdgcn_mfma_f32_16x16x32_bf16(a2, b2, accH[ni], 0, 0, 0);
            }
        }

        // epilogue: h_t = (1-z)*sumh + z*pre, all in-register per C-cell
        float* h_t = h + (size_t)(1 + t * E_) * H_;
#pragma unroll
        for (int reg = 0; reg < 4; ++reg) {
            const int r = quad * 4 + reg;
            const int xr = xw[r];
#pragma unroll
            for (int ni = 0; ni < 2; ++ni) {
                const int col = n0 + ni * 16 + c;
                const unsigned zh = eWzh[(size_t)xr * H_ + col];
                const float z   = fsig(accZ[ni][reg] + hu_h(zh));
                const float pre = ftanh(accH[ni][reg] + hu_u(zh));
                const float hv = (1.0f - z) * bf2f((unsigned short)shB[r][col]) + z * pre;
                h_t[(size_t)(e0 + r) * H_ + col] = hv;
                hB[r][col] = f2bf(hv);
            }
        }

        if (t < T_ - 1) {
            __syncthreads();
            // ---- Ur MFMA: u = h_t @ Ur; store packed {h_bf16, u_bf16} ----
            f32x4 accU[2];
            accU[0] = (f32x4)(0.0f); accU[1] = (f32x4)(0.0f);
#pragma unroll
            for (int k0 = 0; k0 < H_; k0 += 32) {
                const bf16x8 a = *(const bf16x8*)&hB[c][k0 + kq];
#pragma unroll
                for (int ni = 0; ni < 2; ++ni) {
                    const bf16x8 b = *(const bf16x8*)(Urt + (size_t)(n0 + ni * 16 + c) * H_ + k0 + kq);
                    accU[ni] = __builtin_amdgcn_mfma_f32_16x16x32_bf16(a, b, accU[ni], 0, 0, 0);
                }
            }
            unsigned* hu_t = hu + (size_t)(1 + t * E_) * H_;
#pragma unroll
            for (int reg = 0; reg < 4; ++reg) {
                const int r = quad * 4 + reg;
#pragma unroll
                for (int ni = 0; ni < 2; ++ni) {
                    const int col = n0 + ni * 16 + c;
                    const unsigned ubits = (unsigned)(unsigned short)f2bf(accU[ni][reg]);
                    const unsigned hbits = (unsigned)(unsigned short)hB[r][col];
                    hu_t[(size_t)(e0 + r) * H_ + col] = (ubits << 16) | hbits;
                }
            }
        }

        gbar(bar, (unsigned)(t + 1) * NBLK);
    }

    // ---- root tail: blocks 0..255, root_vecs[b] = relu(eWo[wid] + sum_nei @ Wo_bot) ----
    if (blockIdx.x < B_) {
        const int b = blockIdx.x, d = tid;
        float* sn = (float*)&shB[0][0];     // reuse LDS
        int* ridx = &idx[0][0];
        if (d < NB_) ridx[d] = root_nei[b * NB_ + d];
        __syncthreads();
        if (d < H_) {
            float s = 0.0f;
#pragma unroll
            for (int j = 0; j < NB_; ++j) s += h[(size_t)ridx[j] * H_ + d];
            sn[d] = s;
        }
        __syncthreads();
        if (d < H_) {
            float acc = eWo[(size_t)root_wid[b] * H_ + d];
            for (int k = 0; k < H_; ++k)
                acc = fmaf(sn[k], Wo[(size_t)(H_ + k) * H_ + d], acc);
            root_out[(size_t)b * H_ + d] = fmaxf(acc, 0.0f);
        }
    }
}

extern "C" void kernel_launch(void* const* d_in, const int* in_sizes, int n_in,
                              void* d_out, int out_size, void* d_ws, size_t ws_size,
                              hipStream_t stream)
{
    const int*   x_ids    = (const int*)d_in[0];
    const int*   nei_idx  = (const int*)d_in[1];
    const int*   root_wid = (const int*)d_in[2];
    const int*   root_nei = (const int*)d_in[3];
    const float* emb      = (const float*)d_in[4];
    const float* Wz       = (const float*)d_in[5];
    const float* bz       = (const float*)d_in[6];
    const float* Wr       = (const float*)d_in[7];
    const float* Ur       = (const float*)d_in[8];
    const float* bur      = (const float*)d_in[9];
    const float* Wh       = (const float*)d_in[10];
    const float* bh       = (const float*)d_in[11];
    const float* Wo       = (const float*)d_in[12];
    const float* bo       = (const float*)d_in[13];

    float* h        = (float*)d_out;                      // [(1+M), H]
    float* root_out = h + (size_t)(1 + M_) * H_;          // [B, H]

    unsigned* hu = (unsigned*)d_ws;                       // [(1+M), H] packed {h,u} bf16
    float* eWr  = (float*)(hu + (size_t)(1 + M_) * H_);   // [V, H] emb@Wr + bur
    float* eWz  = eWr  + (size_t)V_ * H_;                 // [V, H] emb@Wz_top + bz
    float* eWh  = eWz  + (size_t)V_ * H_;                 // [V, H] emb@Wh_top + bh
    float* eWo  = eWh  + (size_t)V_ * H_;                 // [V, H] emb@Wo_top + bo
    short* Wzt  = (short*)(eWo + (size_t)V_ * H_);        // [256,256] bf16 transposed
    short* Wht  = Wzt + 65536;
    short* Urt  = Wht + 65536;
    unsigned* eWzh = (unsigned*)(Urt + 65536);            // [V, H] packed {bf16(eWz), bf16(eWh)}
    unsigned* bar  = eWzh + (size_t)V_ * H_;              // [1] grid-barrier counter

    k_wconv<<<dim3(769), dim3(256), 0, stream>>>(Wz, Wh, Ur, Wzt, Wht, Urt, h, hu, bar);
    gemm_pre<<<dim3((V_ + 63) / 64, 4, 4), dim3(256), 0, stream>>>(
        emb, Wr, Wz, Wh, Wo, bur, bz, bh, bo, eWr, eWz, eWh, eWo);
    k_pack<<<dim3(V_ * H_ / 256), dim3(256), 0, stream>>>(eWz, eWh, eWzh);

    k_steps_all<<<dim3(NBLK), dim3(512), 0, stream>>>(
        x_ids, nei_idx, h, hu, eWr, eWzh, Wzt, Wht, Urt,
        root_wid, root_nei, eWo, Wo, root_out, bar);
}

// Round 5
// 1399.531 us; speedup vs baseline: 1.7415x; 1.7415x over previous
//
#include <hip/hip_runtime.h>
#include <hip/hip_bf16.h>
#include <math.h>

#define T_ 12
#define E_ 8192
#define H_ 256
#define V_ 800
#define B_ 256
#define NB_ 8
#define M_ (T_*E_)
#define TM 16            // message rows per block per step
#define HP (H_ + 8)      // bf16 LDS row pad
#define NBLK 512         // persistent grid: 2 blocks/CU on 256 CUs (proven resident in R4)

typedef __attribute__((ext_vector_type(8))) short bf16x8;
typedef __attribute__((ext_vector_type(4))) float f32x4;

#define LOG2E_ 1.44269504088896f

// fast native transcendentals (v_exp_f32 = 2^x, v_rcp_f32)
__device__ __forceinline__ float fexp2_(float x) { return __builtin_amdgcn_exp2f(x); }
__device__ __forceinline__ float frcp_(float x)  { return __builtin_amdgcn_rcpf(x); }
__device__ __forceinline__ float fsig(float x) {
    return frcp_(1.0f + fexp2_(-LOG2E_ * x));
}
__device__ __forceinline__ float ftanh(float x) {
    // tanh(x) = 1 - 2/(exp(2x)+1); large |x| saturates correctly via inf/0
    return 1.0f - 2.0f * frcp_(fexp2_(2.0f * LOG2E_ * x) + 1.0f);
}

// RNE f32 -> bf16 bits
__device__ __forceinline__ short f2bf(float x) {
    unsigned u = __float_as_uint(x);
    unsigned r = (u + 0x7fffu + ((u >> 16) & 1u)) >> 16;
    return (short)r;
}
__device__ __forceinline__ float bf2f(unsigned short s) {
    return __uint_as_float(((unsigned)s) << 16);
}
// packed word: lo16 -> float via <<16, hi16 -> float via mask
__device__ __forceinline__ float hu_h(unsigned v) { return __uint_as_float(v << 16); }
__device__ __forceinline__ float hu_u(unsigned v) { return __uint_as_float(v & 0xffff0000u); }
__device__ __forceinline__ unsigned pack2(float a, float b) {
    return (unsigned)(unsigned short)f2bf(a) | ((unsigned)(unsigned short)f2bf(b) << 16);
}

// Device-scope grid barrier for a fully-resident grid.
// R4's version polled with ACQUIRE (cache-invalidate per iteration) and fenced in
// every thread -> chip-wide cache destruction (2313us, 706 GB/s grind). Fixed:
//  - thread0-only __threadfence BEFORE arrival (release: wb this block's stores)
//  - RELAXED agent-scope poll (reads coherence point, NO cache maintenance)
//  - thread0-only __threadfence AFTER spin (acquire: one L1/L2 invalidate);
//    cache ops are cache-wide, __syncthreads publishes to the whole block.
__device__ __forceinline__ void gbar(unsigned* cnt, unsigned target) {
    __syncthreads();
    if (threadIdx.x == 0) {
        __threadfence();                                   // release
        __hip_atomic_fetch_add(cnt, 1u, __ATOMIC_RELAXED, __HIP_MEMORY_SCOPE_AGENT);
        while (__hip_atomic_load(cnt, __ATOMIC_RELAXED, __HIP_MEMORY_SCOPE_AGENT) < target)
            __builtin_amdgcn_s_sleep(16);
        __threadfence();                                   // acquire (one inv)
    }
    __syncthreads();
}

// Weight prep (+ slot-0 init and barrier-counter reset folded into block 768).
// Wzt[n][k] = Wz[256+k][n], Wht[n][k] = Wh[256+k][n], Urt[n][k] = Ur[k][n], bf16.
__global__ __launch_bounds__(256) void k_wconv(
    const float* __restrict__ Wz, const float* __restrict__ Wh, const float* __restrict__ Ur,
    short* __restrict__ Wzt, short* __restrict__ Wht, short* __restrict__ Urt,
    float* __restrict__ h, unsigned* __restrict__ hu, unsigned* __restrict__ bar)
{
    if (blockIdx.x == 768) {            // zero padding row (slot 0) of h and hu
        h[threadIdx.x] = 0.0f;
        hu[threadIdx.x] = 0u;
        if (threadIdx.x == 0) bar[0] = 0u;   // re-zero barrier each graph replay
        return;
    }
    int tid = blockIdx.x * 256 + threadIdx.x;
    int w = tid >> 16;
    int idx = tid & 65535;
    int n = idx >> 8, k = idx & 255;
    if (w == 0)      Wzt[idx] = f2bf(Wz[(size_t)(256 + k) * H_ + n]);
    else if (w == 1) Wht[idx] = f2bf(Wh[(size_t)(256 + k) * H_ + n]);
    else             Urt[idx] = f2bf(Ur[(size_t)k * H_ + n]);
}

// Batched prelude: eW*[v] = emb[v] @ Btop + bias  (blockIdx.z selects table)
__global__ __launch_bounds__(256) void gemm_pre(
    const float* __restrict__ emb,
    const float* __restrict__ Wr, const float* __restrict__ Wz,
    const float* __restrict__ Wh, const float* __restrict__ Wo,
    const float* __restrict__ bur, const float* __restrict__ bz,
    const float* __restrict__ bh, const float* __restrict__ bo,
    float* __restrict__ eWr, float* __restrict__ eWz,
    float* __restrict__ eWh, float* __restrict__ eWo)
{
    const float* Bm; const float* bias; float* C;
    switch (blockIdx.z) {
        case 0: Bm = Wr; bias = bur; C = eWr; break;
        case 1: Bm = Wz; bias = bz;  C = eWz; break;
        case 2: Bm = Wh; bias = bh;  C = eWh; break;
        default: Bm = Wo; bias = bo; C = eWo; break;
    }
    __shared__ float As[16][64];
    __shared__ float Bs[16][64];
    const int tid = threadIdx.x;
    const int bm = blockIdx.x * 64;
    const int bn = blockIdx.y * 64;
    const int a_m = tid & 63;
    const int a_k = (tid >> 6) << 2;
    const int b_k = tid >> 4;
    const int b_n = (tid & 15) << 2;
    const int tx = tid & 15, ty = tid >> 4;

    float acc[4][4] = {};
    const bool a_ok = (bm + a_m) < V_;
    const float* Ap = emb + (size_t)(bm + a_m) * H_ + a_k;
    const float* Bp = Bm + (size_t)b_k * H_ + bn + b_n;

    for (int k0 = 0; k0 < H_; k0 += 16) {
        float4 av = a_ok ? *(const float4*)(Ap + k0) : make_float4(0.f, 0.f, 0.f, 0.f);
        float4 bv = *(const float4*)(Bp + (size_t)k0 * H_);
        __syncthreads();
        As[a_k + 0][a_m] = av.x;
        As[a_k + 1][a_m] = av.y;
        As[a_k + 2][a_m] = av.z;
        As[a_k + 3][a_m] = av.w;
        *(float4*)&Bs[b_k][b_n] = bv;
        __syncthreads();
#pragma unroll
        for (int k = 0; k < 16; ++k) {
            const float4 a4 = *(const float4*)&As[k][ty << 2];
            const float4 b4 = *(const float4*)&Bs[k][tx << 2];
            const float ar[4] = {a4.x, a4.y, a4.z, a4.w};
            const float br[4] = {b4.x, b4.y, b4.z, b4.w};
#pragma unroll
            for (int i = 0; i < 4; ++i)
#pragma unroll
                for (int j = 0; j < 4; ++j)
                    acc[i][j] = fmaf(ar[i], br[j], acc[i][j]);
        }
    }

    const int col = bn + (tx << 2);
#pragma unroll
    for (int i = 0; i < 4; ++i) {
        const int row = bm + (ty << 2) + i;
        if (row >= V_) break;
        *(float4*)(C + (size_t)row * H_ + col) =
            make_float4(acc[i][0] + bias[col], acc[i][1] + bias[col + 1],
                        acc[i][2] + bias[col + 2], acc[i][3] + bias[col + 3]);
    }
}

// Pack epilogue tables: eWzh = {lo16: bf16(eWz), hi16: bf16(eWh)}
__global__ __launch_bounds__(256) void k_pack(
    const float* __restrict__ eWz, const float* __restrict__ eWh,
    unsigned* __restrict__ eWzh)
{
    const int i = blockIdx.x * 256 + threadIdx.x;   // V_*H_ = 204800 = 800*256
    eWzh[i] = pack2(eWz[i], eWh[i]);
}

// Persistent kernel: all 12 steps + root aggregation, fixed grid barrier between
// steps. 512 blocks x 512 threads, 26.1 KB LDS, 64 VGPR -> 2 blocks/CU resident
// (proven by R4's correct completion).
__global__ __launch_bounds__(512, 4) void k_steps_all(
    const int* __restrict__ x_ids, const int* __restrict__ nei_idx,
    float* __restrict__ h, unsigned* __restrict__ hu,
    const float* __restrict__ eWr, const unsigned* __restrict__ eWzh,
    const short* __restrict__ Wzt, const short* __restrict__ Wht,
    const short* __restrict__ Urt,
    const int* __restrict__ root_wid, const int* __restrict__ root_nei,
    const float* __restrict__ eWo, const float* __restrict__ Wo,
    float* __restrict__ root_out, unsigned* __restrict__ bar)
{
    __shared__ int   idx[TM][NB_];
    __shared__ int   xw[TM];
    __shared__ short shB[TM][HP];   // sumh bf16 (A-frag + epilogue linear term)
    __shared__ short sgB[TM][HP];   // sumg bf16 (A-frag)
    __shared__ short hB[TM][HP];    // h_t bf16 (A-frag Ur + hu pack)

    const int tid = threadIdx.x;
    const int e0 = blockIdx.x * TM;
    const int lane = tid & 63;
    const int wave = tid >> 6;           // 0..7
    const int n0 = wave * 32;
    const int quad = lane >> 4, c = lane & 15;
    const int kq = quad * 8;

    for (int t = 0; t < T_; ++t) {
        if (tid < TM * NB_) {
            int r = tid >> 3, j = tid & 7;
            idx[r][j] = nei_idx[((size_t)t * E_ + e0 + r) * NB_ + j];
        }
        if (tid < TM) xw[tid] = x_ids[t * E_ + e0 + tid];
        __syncthreads();

        // ---- gather: thread = (4-col group, row pair); uint4 loads, 16 in flight ----
        {
            const int c0 = (tid & 63) * 4;       // 64 col-groups x 4 cols = 256 cols
            const int ra = (tid >> 6) * 2;       // 8 row-pairs = 16 rows
            const int rb = ra + 1;
            if (t == 0) {
                // all neighbor slots are the zero pad at t=0
                *(uint2*)&shB[ra][c0] = make_uint2(0u, 0u);
                *(uint2*)&sgB[ra][c0] = make_uint2(0u, 0u);
                *(uint2*)&shB[rb][c0] = make_uint2(0u, 0u);
                *(uint2*)&sgB[rb][c0] = make_uint2(0u, 0u);
            } else {
                uint4 va[NB_], vb[NB_];
#pragma unroll
                for (int j = 0; j < NB_; ++j)
                    va[j] = *(const uint4*)(hu + (size_t)idx[ra][j] * H_ + c0);
#pragma unroll
                for (int j = 0; j < NB_; ++j)
                    vb[j] = *(const uint4*)(hu + (size_t)idx[rb][j] * H_ + c0);
                const float4 r1a = *(const float4*)(eWr + (size_t)xw[ra] * H_ + c0);
                const float4 r1b = *(const float4*)(eWr + (size_t)xw[rb] * H_ + c0);

                float sa0 = 0.f, sa1 = 0.f, sa2 = 0.f, sa3 = 0.f;
                float ga0 = 0.f, ga1 = 0.f, ga2 = 0.f, ga3 = 0.f;
#pragma unroll
                for (int j = 0; j < NB_; ++j) {
                    const float h0 = hu_h(va[j].x); sa0 += h0;
                    ga0 = fmaf(fsig(r1a.x + hu_u(va[j].x)), h0, ga0);
                    const float h1 = hu_h(va[j].y); sa1 += h1;
                    ga1 = fmaf(fsig(r1a.y + hu_u(va[j].y)), h1, ga1);
                    const float h2 = hu_h(va[j].z); sa2 += h2;
                    ga2 = fmaf(fsig(r1a.z + hu_u(va[j].z)), h2, ga2);
                    const float h3 = hu_h(va[j].w); sa3 += h3;
                    ga3 = fmaf(fsig(r1a.w + hu_u(va[j].w)), h3, ga3);
                }
                *(uint2*)&shB[ra][c0] = make_uint2(pack2(sa0, sa1), pack2(sa2, sa3));
                *(uint2*)&sgB[ra][c0] = make_uint2(pack2(ga0, ga1), pack2(ga2, ga3));

                float sb0 = 0.f, sb1 = 0.f, sb2 = 0.f, sb3 = 0.f;
                float gb0 = 0.f, gb1 = 0.f, gb2 = 0.f, gb3 = 0.f;
#pragma unroll
                for (int j = 0; j < NB_; ++j) {
                    const float h0 = hu_h(vb[j].x); sb0 += h0;
                    gb0 = fmaf(fsig(r1b.x + hu_u(vb[j].x)), h0, gb0);
                    const float h1 = hu_h(vb[j].y); sb1 += h1;
                    gb1 = fmaf(fsig(r1b.y + hu_u(vb[j].y)), h1, gb1);
                    const float h2 = hu_h(vb[j].z); sb2 += h2;
                    gb2 = fmaf(fsig(r1b.z + hu_u(vb[j].z)), h2, gb2);
                    const float h3 = hu_h(vb[j].w); sb3 += h3;
                    gb3 = fmaf(fsig(r1b.w + hu_u(vb[j].w)), h3, gb3);
                }
                *(uint2*)&shB[rb][c0] = make_uint2(pack2(sb0, sb1), pack2(sb2, sb3));
                *(uint2*)&sgB[rb][c0] = make_uint2(pack2(gb0, gb1), pack2(gb2, gb3));
            }
        }
        __syncthreads();

        // ---- MFMA + in-register epilogue: wave owns 32-col strip, both Z and H ----
        f32x4 accZ[2], accH[2];
#pragma unroll
        for (int i = 0; i < 2; ++i) { accZ[i] = (f32x4)(0.0f); accH[i] = (f32x4)(0.0f); }

#pragma unroll
        for (int k0 = 0; k0 < H_; k0 += 32) {
            const bf16x8 a1 = *(const bf16x8*)&shB[c][k0 + kq];
            const bf16x8 a2 = *(const bf16x8*)&sgB[c][k0 + kq];
#pragma unroll
            for (int ni = 0; ni < 2; ++ni) {
                const size_t boff = (size_t)(n0 + ni * 16 + c) * H_ + k0 + kq;
                const bf16x8 b1 = *(const bf16x8*)(Wzt + boff);
                const bf16x8 b2 = *(const bf16x8*)(Wht + boff);
                accZ[ni] = __builtin_amdgcn_mfma_f32_16x16x32_bf16(a1, b1, accZ[ni], 0, 0, 0);
                accH[ni] = __builtin_amdgcn_mfma_f32_16x16x32_bf16(a2, b2, accH[ni], 0, 0, 0);
            }
        }

        // epilogue: h_t = (1-z)*sumh + z*pre, all in-register per C-cell.
        // h stores are non-temporal: nothing re-reads h except the tiny root tail,
        // and keeping it out of L2/L3 preserves the hu gather working set.
        float* h_t = h + (size_t)(1 + t * E_) * H_;
#pragma unroll
        for (int reg = 0; reg < 4; ++reg) {
            const int r = quad * 4 + reg;
            const int xr = xw[r];
#pragma unroll
            for (int ni = 0; ni < 2; ++ni) {
                const int col = n0 + ni * 16 + c;
                const unsigned zh = eWzh[(size_t)xr * H_ + col];
                const float z   = fsig(accZ[ni][reg] + hu_h(zh));
                const float pre = ftanh(accH[ni][reg] + hu_u(zh));
                const float hv = (1.0f - z) * bf2f((unsigned short)shB[r][col]) + z * pre;
                __builtin_nontemporal_store(hv, &h_t[(size_t)(e0 + r) * H_ + col]);
                hB[r][col] = f2bf(hv);
            }
        }

        if (t < T_ - 1) {
            __syncthreads();
            // ---- Ur MFMA: u = h_t @ Ur; store packed {h_bf16, u_bf16} ----
            f32x4 accU[2];
            accU[0] = (f32x4)(0.0f); accU[1] = (f32x4)(0.0f);
#pragma unroll
            for (int k0 = 0; k0 < H_; k0 += 32) {
                const bf16x8 a = *(const bf16x8*)&hB[c][k0 + kq];
#pragma unroll
                for (int ni = 0; ni < 2; ++ni) {
                    const bf16x8 b = *(const bf16x8*)(Urt + (size_t)(n0 + ni * 16 + c) * H_ + k0 + kq);
                    accU[ni] = __builtin_amdgcn_mfma_f32_16x16x32_bf16(a, b, accU[ni], 0, 0, 0);
                }
            }
            unsigned* hu_t = hu + (size_t)(1 + t * E_) * H_;
#pragma unroll
            for (int reg = 0; reg < 4; ++reg) {
                const int r = quad * 4 + reg;
#pragma unroll
                for (int ni = 0; ni < 2; ++ni) {
                    const int col = n0 + ni * 16 + c;
                    const unsigned ubits = (unsigned)(unsigned short)f2bf(accU[ni][reg]);
                    const unsigned hbits = (unsigned)(unsigned short)hB[r][col];
                    hu_t[(size_t)(e0 + r) * H_ + col] = (ubits << 16) | hbits;
                }
            }
        }

        gbar(bar, (unsigned)(t + 1) * NBLK);
    }

    // ---- root tail: blocks 0..255, root_vecs[b] = relu(eWo[wid] + sum_nei @ Wo_bot) ----
    if (blockIdx.x < B_) {
        const int b = blockIdx.x, d = tid;
        float* sn = (float*)&shB[0][0];     // reuse LDS
        int* ridx = &idx[0][0];
        if (d < NB_) ridx[d] = root_nei[b * NB_ + d];
        __syncthreads();
        if (d < H_) {
            float s = 0.0f;
#pragma unroll
            for (int j = 0; j < NB_; ++j) s += h[(size_t)ridx[j] * H_ + d];
            sn[d] = s;
        }
        __syncthreads();
        if (d < H_) {
            float acc = eWo[(size_t)root_wid[b] * H_ + d];
            for (int k = 0; k < H_; ++k)
                acc = fmaf(sn[k], Wo[(size_t)(H_ + k) * H_ + d], acc);
            root_out[(size_t)b * H_ + d] = fmaxf(acc, 0.0f);
        }
    }
}

extern "C" void kernel_launch(void* const* d_in, const int* in_sizes, int n_in,
                              void* d_out, int out_size, void* d_ws, size_t ws_size,
                              hipStream_t stream)
{
    const int*   x_ids    = (const int*)d_in[0];
    const int*   nei_idx  = (const int*)d_in[1];
    const int*   root_wid = (const int*)d_in[2];
    const int*   root_nei = (const int*)d_in[3];
    const float* emb      = (const float*)d_in[4];
    const float* Wz       = (const float*)d_in[5];
    const float* bz       = (const float*)d_in[6];
    const float* Wr       = (const float*)d_in[7];
    const float* Ur       = (const float*)d_in[8];
    const float* bur      = (const float*)d_in[9];
    const float* Wh       = (const float*)d_in[10];
    const float* bh       = (const float*)d_in[11];
    const float* Wo       = (const float*)d_in[12];
    const float* bo       = (const float*)d_in[13];

    float* h        = (float*)d_out;                      // [(1+M), H]
    float* root_out = h + (size_t)(1 + M_) * H_;          // [B, H]

    unsigned* hu = (unsigned*)d_ws;                       // [(1+M), H] packed {h,u} bf16
    float* eWr  = (float*)(hu + (size_t)(1 + M_) * H_);   // [V, H] emb@Wr + bur
    float* eWz  = eWr  + (size_t)V_ * H_;                 // [V, H] emb@Wz_top + bz
    float* eWh  = eWz  + (size_t)V_ * H_;                 // [V, H] emb@Wh_top + bh
    float* eWo  = eWh  + (size_t)V_ * H_;                 // [V, H] emb@Wo_top + bo
    short* Wzt  = (short*)(eWo + (size_t)V_ * H_);        // [256,256] bf16 transposed
    short* Wht  = Wzt + 65536;
    short* Urt  = Wht + 65536;
    unsigned* eWzh = (unsigned*)(Urt + 65536);            // [V, H] packed {bf16(eWz), bf16(eWh)}
    unsigned* bar  = eWzh + (size_t)V_ * H_;              // [1] grid-barrier counter

    k_wconv<<<dim3(769), dim3(256), 0, stream>>>(Wz, Wh, Ur, Wzt, Wht, Urt, h, hu, bar);
    gemm_pre<<<dim3((V_ + 63) / 64, 4, 4), dim3(256), 0, stream>>>(
        emb, Wr, Wz, Wh, Wo, bur, bz, bh, bo, eWr, eWz, eWh, eWo);
    k_pack<<<dim3(V_ * H_ / 256), dim3(256), 0, stream>>>(eWz, eWh, eWzh);

    k_steps_all<<<dim3(NBLK), dim3(512), 0, stream>>>(
        x_ids, nei_idx, h, hu, eWr, eWzh, Wzt, Wht, Urt,
        root_wid, root_nei, eWo, Wo, root_out, bar);
}

// Round 6
// 1117.676 us; speedup vs baseline: 2.1807x; 1.2522x over previous
//
#include <hip/hip_runtime.h>
#include <hip/hip_bf16.h>
#include <math.h>

#define T_ 12
#define E_ 8192
#define H_ 256
#define V_ 800
#define B_ 256
#define NB_ 8
#define M_ (T_*E_)
#define TM 16            // message rows per block per step
#define HP (H_ + 8)      // bf16 LDS row pad
#define NBLK 512         // persistent grid: 2 blocks/CU on 256 CUs (proven resident in R4/R5)

typedef __attribute__((ext_vector_type(8))) short bf16x8;
typedef __attribute__((ext_vector_type(4))) float f32x4;
typedef unsigned long long u64;

#define LOG2E_ 1.44269504088896f

// fast native transcendentals (v_exp_f32 = 2^x, v_rcp_f32)
__device__ __forceinline__ float fexp2_(float x) { return __builtin_amdgcn_exp2f(x); }
__device__ __forceinline__ float frcp_(float x)  { return __builtin_amdgcn_rcpf(x); }
__device__ __forceinline__ float fsig(float x) {
    return frcp_(1.0f + fexp2_(-LOG2E_ * x));
}
__device__ __forceinline__ float ftanh(float x) {
    // tanh(x) = 1 - 2/(exp(2x)+1); large |x| saturates correctly via inf/0
    return 1.0f - 2.0f * frcp_(fexp2_(2.0f * LOG2E_ * x) + 1.0f);
}

// RNE f32 -> bf16 bits
__device__ __forceinline__ short f2bf(float x) {
    unsigned u = __float_as_uint(x);
    unsigned r = (u + 0x7fffu + ((u >> 16) & 1u)) >> 16;
    return (short)r;
}
__device__ __forceinline__ float bf2f(unsigned short s) {
    return __uint_as_float(((unsigned)s) << 16);
}
// packed word: lo16 -> float via <<16, hi16 -> float via mask
__device__ __forceinline__ float hu_h(unsigned v) { return __uint_as_float(v << 16); }
__device__ __forceinline__ float hu_u(unsigned v) { return __uint_as_float(v & 0xffff0000u); }
__device__ __forceinline__ unsigned pack2(float a, float b) {
    return (unsigned)(unsigned short)f2bf(a) | ((unsigned)(unsigned short)f2bf(b) << 16);
}

// Agent-scope (device-coherent) accessors for CROSS-BLOCK data only.
// These bypass the non-coherent L1/L2 and hit the coherence point, so the grid
// barrier needs NO __threadfence (R5's per-block fence L2-invalidates were the
// 2.4GB refetch grind). Read-only weights/tables keep normal cached loads and
// stay L2-warm across all 12 steps.
__device__ __forceinline__ u64 co_load64(const unsigned* p) {
    return __hip_atomic_load((const u64*)p, __ATOMIC_RELAXED, __HIP_MEMORY_SCOPE_AGENT);
}
__device__ __forceinline__ void co_store32(unsigned* p, unsigned v) {
    __hip_atomic_store(p, v, __ATOMIC_RELAXED, __HIP_MEMORY_SCOPE_AGENT);
}
__device__ __forceinline__ void co_storef(float* p, float v) {
    __hip_atomic_store((unsigned*)p, __float_as_uint(v), __ATOMIC_RELAXED, __HIP_MEMORY_SCOPE_AGENT);
}
__device__ __forceinline__ float co_loadf(const float* p) {
    return __uint_as_float(__hip_atomic_load((const unsigned*)p, __ATOMIC_RELAXED, __HIP_MEMORY_SCOPE_AGENT));
}

// Fence-free grid barrier for a fully-resident grid. Correctness: __syncthreads
// drains each wave's vmcnt (coherent hu/h stores complete at the coherence point
// before any wave passes), so counter==target implies all blocks' cross-step data
// is globally visible to agent-scope loads. No cache maintenance anywhere.
__device__ __forceinline__ void gbar(unsigned* cnt, unsigned target) {
    __syncthreads();
    if (threadIdx.x == 0) {
        __hip_atomic_fetch_add(cnt, 1u, __ATOMIC_RELAXED, __HIP_MEMORY_SCOPE_AGENT);
        while (__hip_atomic_load(cnt, __ATOMIC_RELAXED, __HIP_MEMORY_SCOPE_AGENT) < target)
            __builtin_amdgcn_s_sleep(8);
    }
    __syncthreads();
}

// Weight prep (+ slot-0 init and barrier-counter reset folded into block 768).
// Wzt[n][k] = Wz[256+k][n], Wht[n][k] = Wh[256+k][n], Urt[n][k] = Ur[k][n], bf16.
__global__ __launch_bounds__(256) void k_wconv(
    const float* __restrict__ Wz, const float* __restrict__ Wh, const float* __restrict__ Ur,
    short* __restrict__ Wzt, short* __restrict__ Wht, short* __restrict__ Urt,
    float* __restrict__ h, unsigned* __restrict__ hu, unsigned* __restrict__ bar)
{
    if (blockIdx.x == 768) {            // zero padding row (slot 0) of h and hu
        h[threadIdx.x] = 0.0f;
        hu[threadIdx.x] = 0u;
        if (threadIdx.x == 0) bar[0] = 0u;   // re-zero barrier each graph replay
        return;
    }
    int tid = blockIdx.x * 256 + threadIdx.x;
    int w = tid >> 16;
    int idx = tid & 65535;
    int n = idx >> 8, k = idx & 255;
    if (w == 0)      Wzt[idx] = f2bf(Wz[(size_t)(256 + k) * H_ + n]);
    else if (w == 1) Wht[idx] = f2bf(Wh[(size_t)(256 + k) * H_ + n]);
    else             Urt[idx] = f2bf(Ur[(size_t)k * H_ + n]);
}

// Batched prelude: eW*[v] = emb[v] @ Btop + bias  (blockIdx.z selects table)
__global__ __launch_bounds__(256) void gemm_pre(
    const float* __restrict__ emb,
    const float* __restrict__ Wr, const float* __restrict__ Wz,
    const float* __restrict__ Wh, const float* __restrict__ Wo,
    const float* __restrict__ bur, const float* __restrict__ bz,
    const float* __restrict__ bh, const float* __restrict__ bo,
    float* __restrict__ eWr, float* __restrict__ eWz,
    float* __restrict__ eWh, float* __restrict__ eWo)
{
    const float* Bm; const float* bias; float* C;
    switch (blockIdx.z) {
        case 0: Bm = Wr; bias = bur; C = eWr; break;
        case 1: Bm = Wz; bias = bz;  C = eWz; break;
        case 2: Bm = Wh; bias = bh;  C = eWh; break;
        default: Bm = Wo; bias = bo; C = eWo; break;
    }
    __shared__ float As[16][64];
    __shared__ float Bs[16][64];
    const int tid = threadIdx.x;
    const int bm = blockIdx.x * 64;
    const int bn = blockIdx.y * 64;
    const int a_m = tid & 63;
    const int a_k = (tid >> 6) << 2;
    const int b_k = tid >> 4;
    const int b_n = (tid & 15) << 2;
    const int tx = tid & 15, ty = tid >> 4;

    float acc[4][4] = {};
    const bool a_ok = (bm + a_m) < V_;
    const float* Ap = emb + (size_t)(bm + a_m) * H_ + a_k;
    const float* Bp = Bm + (size_t)b_k * H_ + bn + b_n;

    for (int k0 = 0; k0 < H_; k0 += 16) {
        float4 av = a_ok ? *(const float4*)(Ap + k0) : make_float4(0.f, 0.f, 0.f, 0.f);
        float4 bv = *(const float4*)(Bp + (size_t)k0 * H_);
        __syncthreads();
        As[a_k + 0][a_m] = av.x;
        As[a_k + 1][a_m] = av.y;
        As[a_k + 2][a_m] = av.z;
        As[a_k + 3][a_m] = av.w;
        *(float4*)&Bs[b_k][b_n] = bv;
        __syncthreads();
#pragma unroll
        for (int k = 0; k < 16; ++k) {
            const float4 a4 = *(const float4*)&As[k][ty << 2];
            const float4 b4 = *(const float4*)&Bs[k][tx << 2];
            const float ar[4] = {a4.x, a4.y, a4.z, a4.w};
            const float br[4] = {b4.x, b4.y, b4.z, b4.w};
#pragma unroll
            for (int i = 0; i < 4; ++i)
#pragma unroll
                for (int j = 0; j < 4; ++j)
                    acc[i][j] = fmaf(ar[i], br[j], acc[i][j]);
        }
    }

    const int col = bn + (tx << 2);
#pragma unroll
    for (int i = 0; i < 4; ++i) {
        const int row = bm + (ty << 2) + i;
        if (row >= V_) break;
        *(float4*)(C + (size_t)row * H_ + col) =
            make_float4(acc[i][0] + bias[col], acc[i][1] + bias[col + 1],
                        acc[i][2] + bias[col + 2], acc[i][3] + bias[col + 3]);
    }
}

// Pack epilogue tables: eWzh = {lo16: bf16(eWz), hi16: bf16(eWh)}
__global__ __launch_bounds__(256) void k_pack(
    const float* __restrict__ eWz, const float* __restrict__ eWh,
    unsigned* __restrict__ eWzh)
{
    const int i = blockIdx.x * 256 + threadIdx.x;   // V_*H_ = 204800 = 800*256
    eWzh[i] = pack2(eWz[i], eWh[i]);
}

// Persistent kernel: all 12 steps + root aggregation, fence-free grid barrier.
// Cross-block data (hu, h) uses agent-coherent accesses; weights/tables stay
// L2-warm for all steps.
__global__ __launch_bounds__(512, 4) void k_steps_all(
    const int* __restrict__ x_ids, const int* __restrict__ nei_idx,
    float* __restrict__ h, unsigned* __restrict__ hu,
    const float* __restrict__ eWr, const unsigned* __restrict__ eWzh,
    const short* __restrict__ Wzt, const short* __restrict__ Wht,
    const short* __restrict__ Urt,
    const int* __restrict__ root_wid, const int* __restrict__ root_nei,
    const float* __restrict__ eWo, const float* __restrict__ Wo,
    float* __restrict__ root_out, unsigned* __restrict__ bar)
{
    __shared__ int   idx[TM][NB_];
    __shared__ int   xw[TM];
    __shared__ short shB[TM][HP];   // sumh bf16 (A-frag + epilogue linear term)
    __shared__ short sgB[TM][HP];   // sumg bf16 (A-frag)
    __shared__ short hB[TM][HP];    // h_t bf16 (A-frag Ur + hu pack)

    const int tid = threadIdx.x;
    const int e0 = blockIdx.x * TM;
    const int lane = tid & 63;
    const int wave = tid >> 6;           // 0..7
    const int n0 = wave * 32;
    const int quad = lane >> 4, c = lane & 15;
    const int kq = quad * 8;

    for (int t = 0; t < T_; ++t) {
        if (tid < TM * NB_) {
            int r = tid >> 3, j = tid & 7;
            idx[r][j] = nei_idx[((size_t)t * E_ + e0 + r) * NB_ + j];
        }
        if (tid < TM) xw[tid] = x_ids[t * E_ + e0 + tid];
        __syncthreads();

        // ---- gather: thread = (4-col group, row pair); coherent 8B loads ----
        {
            const int c0 = (tid & 63) * 4;       // 64 col-groups x 4 cols = 256 cols
            const int ra = (tid >> 6) * 2;       // 8 row-pairs = 16 rows
            const int rb = ra + 1;
            if (t == 0) {
                // all neighbor slots are the zero pad at t=0
                *(uint2*)&shB[ra][c0] = make_uint2(0u, 0u);
                *(uint2*)&sgB[ra][c0] = make_uint2(0u, 0u);
                *(uint2*)&shB[rb][c0] = make_uint2(0u, 0u);
                *(uint2*)&sgB[rb][c0] = make_uint2(0u, 0u);
            } else {
                u64 va0[NB_], va1[NB_], vb0[NB_], vb1[NB_];
#pragma unroll
                for (int j = 0; j < NB_; ++j) {
                    const unsigned* pa = hu + (size_t)idx[ra][j] * H_ + c0;
                    va0[j] = co_load64(pa);
                    va1[j] = co_load64(pa + 2);
                }
#pragma unroll
                for (int j = 0; j < NB_; ++j) {
                    const unsigned* pb = hu + (size_t)idx[rb][j] * H_ + c0;
                    vb0[j] = co_load64(pb);
                    vb1[j] = co_load64(pb + 2);
                }
                const float4 r1a = *(const float4*)(eWr + (size_t)xw[ra] * H_ + c0);
                const float4 r1b = *(const float4*)(eWr + (size_t)xw[rb] * H_ + c0);

                float sa0 = 0.f, sa1 = 0.f, sa2 = 0.f, sa3 = 0.f;
                float ga0 = 0.f, ga1 = 0.f, ga2 = 0.f, ga3 = 0.f;
#pragma unroll
                for (int j = 0; j < NB_; ++j) {
                    const unsigned w0 = (unsigned)va0[j], w1 = (unsigned)(va0[j] >> 32);
                    const unsigned w2 = (unsigned)va1[j], w3 = (unsigned)(va1[j] >> 32);
                    const float h0 = hu_h(w0); sa0 += h0;
                    ga0 = fmaf(fsig(r1a.x + hu_u(w0)), h0, ga0);
                    const float h1 = hu_h(w1); sa1 += h1;
                    ga1 = fmaf(fsig(r1a.y + hu_u(w1)), h1, ga1);
                    const float h2 = hu_h(w2); sa2 += h2;
                    ga2 = fmaf(fsig(r1a.z + hu_u(w2)), h2, ga2);
                    const float h3 = hu_h(w3); sa3 += h3;
                    ga3 = fmaf(fsig(r1a.w + hu_u(w3)), h3, ga3);
                }
                *(uint2*)&shB[ra][c0] = make_uint2(pack2(sa0, sa1), pack2(sa2, sa3));
                *(uint2*)&sgB[ra][c0] = make_uint2(pack2(ga0, ga1), pack2(ga2, ga3));

                float sb0 = 0.f, sb1 = 0.f, sb2 = 0.f, sb3 = 0.f;
                float gb0 = 0.f, gb1 = 0.f, gb2 = 0.f, gb3 = 0.f;
#pragma unroll
                for (int j = 0; j < NB_; ++j) {
                    const unsigned w0 = (unsigned)vb0[j], w1 = (unsigned)(vb0[j] >> 32);
                    const unsigned w2 = (unsigned)vb1[j], w3 = (unsigned)(vb1[j] >> 32);
                    const float h0 = hu_h(w0); sb0 += h0;
                    gb0 = fmaf(fsig(r1b.x + hu_u(w0)), h0, gb0);
                    const float h1 = hu_h(w1); sb1 += h1;
                    gb1 = fmaf(fsig(r1b.y + hu_u(w1)), h1, gb1);
                    const float h2 = hu_h(w2); sb2 += h2;
                    gb2 = fmaf(fsig(r1b.z + hu_u(w2)), h2, gb2);
                    const float h3 = hu_h(w3); sb3 += h3;
                    gb3 = fmaf(fsig(r1b.w + hu_u(w3)), h3, gb3);
                }
                *(uint2*)&shB[rb][c0] = make_uint2(pack2(sb0, sb1), pack2(sb2, sb3));
                *(uint2*)&sgB[rb][c0] = make_uint2(pack2(gb0, gb1), pack2(gb2, gb3));
            }
        }
        __syncthreads();

        // ---- MFMA + in-register epilogue: wave owns 32-col strip, both Z and H ----
        f32x4 accZ[2], accH[2];
#pragma unroll
        for (int i = 0; i < 2; ++i) { accZ[i] = (f32x4)(0.0f); accH[i] = (f32x4)(0.0f); }

#pragma unroll
        for (int k0 = 0; k0 < H_; k0 += 32) {
            const bf16x8 a1 = *(const bf16x8*)&shB[c][k0 + kq];
            const bf16x8 a2 = *(const bf16x8*)&sgB[c][k0 + kq];
#pragma unroll
            for (int ni = 0; ni < 2; ++ni) {
                const size_t boff = (size_t)(n0 + ni * 16 + c) * H_ + k0 + kq;
                const bf16x8 b1 = *(const bf16x8*)(Wzt + boff);
                const bf16x8 b2 = *(const bf16x8*)(Wht + boff);
                accZ[ni] = __builtin_amdgcn_mfma_f32_16x16x32_bf16(a1, b1, accZ[ni], 0, 0, 0);
                accH[ni] = __builtin_amdgcn_mfma_f32_16x16x32_bf16(a2, b2, accH[ni], 0, 0, 0);
            }
        }

        // epilogue: h_t = (1-z)*sumh + z*pre, all in-register per C-cell.
        // h stores are agent-coherent (root tail on another XCD reads them).
        float* h_t = h + (size_t)(1 + t * E_) * H_;
#pragma unroll
        for (int reg = 0; reg < 4; ++reg) {
            const int r = quad * 4 + reg;
            const int xr = xw[r];
#pragma unroll
            for (int ni = 0; ni < 2; ++ni) {
                const int col = n0 + ni * 16 + c;
                const unsigned zh = eWzh[(size_t)xr * H_ + col];
                const float z   = fsig(accZ[ni][reg] + hu_h(zh));
                const float pre = ftanh(accH[ni][reg] + hu_u(zh));
                const float hv = (1.0f - z) * bf2f((unsigned short)shB[r][col]) + z * pre;
                co_storef(&h_t[(size_t)(e0 + r) * H_ + col], hv);
                hB[r][col] = f2bf(hv);
            }
        }

        if (t < T_ - 1) {
            __syncthreads();
            // ---- Ur MFMA: u = h_t @ Ur; store packed {h_bf16, u_bf16} coherently ----
            f32x4 accU[2];
            accU[0] = (f32x4)(0.0f); accU[1] = (f32x4)(0.0f);
#pragma unroll
            for (int k0 = 0; k0 < H_; k0 += 32) {
                const bf16x8 a = *(const bf16x8*)&hB[c][k0 + kq];
#pragma unroll
                for (int ni = 0; ni < 2; ++ni) {
                    const bf16x8 b = *(const bf16x8*)(Urt + (size_t)(n0 + ni * 16 + c) * H_ + k0 + kq);
                    accU[ni] = __builtin_amdgcn_mfma_f32_16x16x32_bf16(a, b, accU[ni], 0, 0, 0);
                }
            }
            unsigned* hu_t = hu + (size_t)(1 + t * E_) * H_;
#pragma unroll
            for (int reg = 0; reg < 4; ++reg) {
                const int r = quad * 4 + reg;
#pragma unroll
                for (int ni = 0; ni < 2; ++ni) {
                    const int col = n0 + ni * 16 + c;
                    const unsigned ubits = (unsigned)(unsigned short)f2bf(accU[ni][reg]);
                    const unsigned hbits = (unsigned)(unsigned short)hB[r][col];
                    co_store32(&hu_t[(size_t)(e0 + r) * H_ + col], (ubits << 16) | hbits);
                }
            }
        }

        gbar(bar, (unsigned)(t + 1) * NBLK);
    }

    // ---- root tail: blocks 0..255, root_vecs[b] = relu(eWo[wid] + sum_nei @ Wo_bot) ----
    if (blockIdx.x < B_) {
        const int b = blockIdx.x, d = tid;
        float* sn = (float*)&shB[0][0];     // reuse LDS
        int* ridx = &idx[0][0];
        if (d < NB_) ridx[d] = root_nei[b * NB_ + d];
        __syncthreads();
        if (d < H_) {
            float s = 0.0f;
#pragma unroll
            for (int j = 0; j < NB_; ++j) s += co_loadf(&h[(size_t)ridx[j] * H_ + d]);
            sn[d] = s;
        }
        __syncthreads();
        if (d < H_) {
            float acc = eWo[(size_t)root_wid[b] * H_ + d];
            for (int k = 0; k < H_; ++k)
                acc = fmaf(sn[k], Wo[(size_t)(H_ + k) * H_ + d], acc);
            root_out[(size_t)b * H_ + d] = fmaxf(acc, 0.0f);
        }
    }
}

extern "C" void kernel_launch(void* const* d_in, const int* in_sizes, int n_in,
                              void* d_out, int out_size, void* d_ws, size_t ws_size,
                              hipStream_t stream)
{
    const int*   x_ids    = (const int*)d_in[0];
    const int*   nei_idx  = (const int*)d_in[1];
    const int*   root_wid = (const int*)d_in[2];
    const int*   root_nei = (const int*)d_in[3];
    const float* emb      = (const float*)d_in[4];
    const float* Wz       = (const float*)d_in[5];
    const float* bz       = (const float*)d_in[6];
    const float* Wr       = (const float*)d_in[7];
    const float* Ur       = (const float*)d_in[8];
    const float* bur      = (const float*)d_in[9];
    const float* Wh       = (const float*)d_in[10];
    const float* bh       = (const float*)d_in[11];
    const float* Wo       = (const float*)d_in[12];
    const float* bo       = (const float*)d_in[13];

    float* h        = (float*)d_out;                      // [(1+M), H]
    float* root_out = h + (size_t)(1 + M_) * H_;          // [B, H]

    unsigned* hu = (unsigned*)d_ws;                       // [(1+M), H] packed {h,u} bf16
    float* eWr  = (float*)(hu + (size_t)(1 + M_) * H_);   // [V, H] emb@Wr + bur
    float* eWz  = eWr  + (size_t)V_ * H_;                 // [V, H] emb@Wz_top + bz
    float* eWh  = eWz  + (size_t)V_ * H_;                 // [V, H] emb@Wh_top + bh
    float* eWo  = eWh  + (size_t)V_ * H_;                 // [V, H] emb@Wo_top + bo
    short* Wzt  = (short*)(eWo + (size_t)V_ * H_);        // [256,256] bf16 transposed
    short* Wht  = Wzt + 65536;
    short* Urt  = Wht + 65536;
    unsigned* eWzh = (unsigned*)(Urt + 65536);            // [V, H] packed {bf16(eWz), bf16(eWh)}
    unsigned* bar  = eWzh + (size_t)V_ * H_;              // [1] grid-barrier counter

    k_wconv<<<dim3(769), dim3(256), 0, stream>>>(Wz, Wh, Ur, Wzt, Wht, Urt, h, hu, bar);
    gemm_pre<<<dim3((V_ + 63) / 64, 4, 4), dim3(256), 0, stream>>>(
        emb, Wr, Wz, Wh, Wo, bur, bz, bh, bo, eWr, eWz, eWh, eWo);
    k_pack<<<dim3(V_ * H_ / 256), dim3(256), 0, stream>>>(eWz, eWh, eWzh);

    k_steps_all<<<dim3(NBLK), dim3(512), 0, stream>>>(
        x_ids, nei_idx, h, hu, eWr, eWzh, Wzt, Wht, Urt,
        root_wid, root_nei, eWo, Wo, root_out, bar);
}